// Round 6
// baseline (1274.393 us; speedup 1.0000x reference)
//
#include <hip/hip_runtime.h>
#include <hip/hip_bf16.h>
#include <stdint.h>

#define DECAY 0.951229424500714f

// problem sizes (fixed by setup_inputs)
#define BATCH 16
#define TSTEPS 16

// ---------------- ws layout (byte offsets) ----------------
// conv-phase state (dead after conv loop; overlaid by split-K partials):
#define OFF_VM0B 0u            // fp32 [16][4096][32] NHWC          8,388,608 B
#define OFF_VM1B 8388608u      // fp32 [16][64][64][64] NCHW       16,777,216 B
#define OFF_S0PB 25165824u     // bf16 [16][32][66][66] padded NCHW 4,460,544 B
#define OFF_W0TB 29626368u     // fp32 [18 (ic*9+tap)][32 oc]           2,304 B
#define OFF_W1TB 29628672u     // fp32 [4 g][32 ic][16 u][12 k-pad]    98,304 B
#define ZERO_BYTES 29626368u   // vm0+vm1+s0p (guard ring must be 0)
// persistent across dense phase:
#define KSPLIT 64
#define KCHUNK (65536 / KSPLIT)        // 1024
#define OFF_PART_BYTES 0u              // fp32 [64][256][512] = 33,554,432 B (overlays dead conv state + W0t/W1t)
#define OFF_I_BYTES 33554432u          // fp32 [256][512] (m = t*16+b)
#define OFF_FLAT_BYTES 34078720u       // bf16 [256][65536]  (ends at 67,633,152 B)

typedef __attribute__((ext_vector_type(8))) short short8;
typedef __attribute__((ext_vector_type(4))) float floatx4;

__device__ inline unsigned short f2bf_rne(float f) {
    unsigned u = __float_as_uint(f);
    unsigned r = (u + 0x7FFFu + ((u >> 16) & 1u)) >> 16;
    return (unsigned short)r;
}
__device__ inline float bf2f(unsigned short h) {
    return __uint_as_float(((unsigned)h) << 16);
}

// ---------------- weight prep (once per call): exact fp32 transposes ----------------
// W1t[g][ic][u][12] (k 0..8 = W1, 9..11 = 0 pad -> 16B-aligned JIT ds_read_b128)
// W0t[(ic*9+tap)][oc]
__global__ __launch_bounds__(256) void prep_weights(const float* __restrict__ W0,
                                                    const float* __restrict__ W1,
                                                    float* __restrict__ ws) {
    int id = blockIdx.x * 256 + threadIdx.x;
    if (id < 24576) {
        int g = id / 6144, rem = id % 6144;
        int ic = rem / 192, rem2 = rem % 192;
        int u = rem2 / 12, k = rem2 % 12;
        int oc = g * 16 + u;
        float* w1t = (float*)((char*)ws + OFF_W1TB);
        w1t[id] = (k < 9) ? W1[((size_t)oc * 32 + ic) * 9 + k] : 0.f;
    } else if (id < 25152) {
        int e = id - 24576;
        int ict = e >> 5, oc = e & 31;      // ict = ic*9 + tap
        int ic = ict / 9, tap = ict % 9;
        float* w0t = (float*)((char*)ws + OFF_W0TB);
        w0t[ict * 32 + oc] = W0[(oc * 2 + ic) * 9 + tap];
    }
}

// ---------------- conv0 (2->32, 3x3, pad 1) + LIF0 -> s0 bf16 padded-NCHW ----------------
// Arithmetic bit-identical to the verified round-0 kernel.
__global__ __launch_bounds__(256) void conv0_lif(const float* __restrict__ in,
                                                 float* __restrict__ ws, int t) {
    int y = blockIdx.x, b = blockIdx.y;
    int tid = threadIdx.x;
    int x = tid & 63;
    int g = __builtin_amdgcn_readfirstlane(tid >> 6);   // oc group (8 oc)
    const float* xin = in + (size_t)((b * TSTEPS + t) * 2) * 4096;
    const float* w0t = (const float*)((const char*)ws + OFF_W0TB);
    float acc[8];
#pragma unroll
    for (int u = 0; u < 8; ++u) acc[u] = 0.f;
#pragma unroll
    for (int ic = 0; ic < 2; ++ic) {
#pragma unroll
        for (int dy = 0; dy < 3; ++dy) {
            int sy = y + dy - 1;
            bool vy = (unsigned)sy < 64u;
            const float* rp = xin + ic * 4096 + sy * 64;
#pragma unroll
            for (int dx = 0; dx < 3; ++dx) {
                int sx = x + dx - 1;
                float v = (vy && (unsigned)sx < 64u) ? rp[sx] : 0.f;
                v = fminf(fmaxf(v, 0.f), 1.f);          // clip(x,0,1)
                const float* wp = w0t + ((ic * 9 + dy * 3 + dx) * 32 + g * 8);
#pragma unroll
                for (int u = 0; u < 8; ++u) acc[u] = fmaf(v, wp[u], acc[u]);
            }
        }
    }
    // LIF0 on vm0 (NHWC fp32); spikes out to padded NCHW bf16 s0 (exact 0.0 / 1.0)
    float* vm0 = (float*)((char*)ws + OFF_VM0B);
    size_t pidx = ((size_t)(b * 4096 + y * 64 + x)) * 32 + g * 8;
    floatx4 v0 = *(floatx4*)(vm0 + pidx);
    floatx4 v1 = *(floatx4*)(vm0 + pidx + 4);
    unsigned short sp[8];
#pragma unroll
    for (int u = 0; u < 4; ++u) {
        float vm = ((v0[u] > 0.5f) ? 0.f : v0[u] * DECAY) + acc[u];
        v0[u] = vm;
        sp[u] = (vm > 0.5f) ? (unsigned short)0x3F80 : (unsigned short)0;
    }
#pragma unroll
    for (int u = 0; u < 4; ++u) {
        float vm = ((v1[u] > 0.5f) ? 0.f : v1[u] * DECAY) + acc[4 + u];
        v1[u] = vm;
        sp[4 + u] = (vm > 0.5f) ? (unsigned short)0x3F80 : (unsigned short)0;
    }
    *(floatx4*)(vm0 + pidx) = v0;
    *(floatx4*)(vm0 + pidx + 4) = v1;
    unsigned short* s0p = (unsigned short*)((char*)ws + OFF_S0PB);
#pragma unroll
    for (int u = 0; u < 8; ++u) {
        int c = g * 8 + u;
        s0p[((size_t)(b * 32 + c) * 66 + (y + 1)) * 66 + (x + 1)] = sp[u];
    }
}

// ---------------- conv1 (32->64, 3x3, pad 1) + LIF1 + fused 2x2 maxpool ----------------
// v4: software-pipelined ic loop (ic+=2 ping-pong vA/vB, next-ic s0 loads issued before
// current-ic compute); weights JIT from LDS (3 ds_read_b128 per oc, hidden under fmas);
// blockIdx.x = b -> XCD = b&7 (s0 of 2 batches per XCD = 558 KB, L2-resident).
// BIT-EXACT: per accumulator the fma chain is sequential fp32, ic ascending (outer),
// k = 0..8 ascending (inner) — identical to the verified round-3/4/5 chain.
__global__ __launch_bounds__(256, 4) void conv1_lif(float* __restrict__ ws, int t) {
    __shared__ float wlds[6144];                 // [ic 32][u 16][12] for this block's g
    __shared__ unsigned short s1_s[4][64][18];   // [row r][x][oc_local] (pitch 18)
    int tid = threadIdx.x;
    int x = tid & 63;
    int sg = __builtin_amdgcn_readfirstlane(tid >> 6);   // oc quad within g (4 oc)
    int b = blockIdx.x, y4 = blockIdx.y, g = blockIdx.z; // batch (XCD key), row-quad, 16-oc group
    int y0 = y4 * 4;

    // ---- stage this g's padded weight slice (6144 floats, coalesced float4) ----
    {
        const float* wsrc = (const float*)((const char*)ws + OFF_W1TB) + (size_t)g * 6144;
#pragma unroll
        for (int i = 0; i < 6; ++i) {
            int e = tid + i * 256;
            *(float4*)&wlds[e * 4] = *(const float4*)&wsrc[e * 4];
        }
    }
    __syncthreads();

    const unsigned short* s0b = (const unsigned short*)((const char*)ws + OFF_S0PB)
                                + (size_t)b * 32 * 4356 + (size_t)y0 * 66 + x;

    float acc[4][4];   // [row r][uu]
#pragma unroll
    for (int r = 0; r < 4; ++r)
#pragma unroll
        for (int uu = 0; uu < 4; ++uu) acc[r][uu] = 0.f;

#define LOADV(dst, icc) do {                                              \
        const unsigned short* sc_ = s0b + (size_t)(icc) * 4356;           \
        _Pragma("unroll")                                                 \
        for (int rr_ = 0; rr_ < 6; ++rr_)                                 \
            _Pragma("unroll")                                             \
            for (int dx_ = 0; dx_ < 3; ++dx_)                             \
                dst[rr_ * 3 + dx_] = bf2f(sc_[rr_ * 66 + dx_]);           \
    } while (0)

    auto compute = [&](const float (&v)[18], int icc) {
        const float* wq = &wlds[icc * 192 + sg * 48];
#pragma unroll
        for (int uu = 0; uu < 4; ++uu) {
            float4 w0 = *(const float4*)&wq[uu * 12 + 0];
            float4 w1 = *(const float4*)&wq[uu * 12 + 4];
            float4 w2 = *(const float4*)&wq[uu * 12 + 8];   // .y/.z/.w = pad, unused
            float wk[9] = {w0.x, w0.y, w0.z, w0.w, w1.x, w1.y, w1.z, w1.w, w2.x};
#pragma unroll
            for (int k = 0; k < 9; ++k) {
                int rr = k / 3, dx = k - rr * 3;
                float w = wk[k];
#pragma unroll
                for (int r = 0; r < 4; ++r)
                    acc[r][uu] = fmaf(v[(rr + r) * 3 + dx], w, acc[r][uu]);
            }
        }
    };

    float vA[18], vB[18];
    LOADV(vA, 0);
    for (int ic = 0; ic < 32; ic += 2) {
        LOADV(vB, ic + 1);
        compute(vA, ic);
        if (ic + 2 < 32) LOADV(vA, ic + 2);
        compute(vB, ic + 1);
    }
#undef LOADV

    // LIF1 on vm1 (NCHW fp32; s_prev = vm_prev > 0.5); spikes to LDS for pooling
    float* vm1 = (float*)((char*)ws + OFF_VM1B);
#pragma unroll
    for (int r = 0; r < 4; ++r) {
#pragma unroll
        for (int uu = 0; uu < 4; ++uu) {
            int ol = sg * 4 + uu;                 // oc_local 0..15
            int oc = g * 16 + ol;
            size_t addr = ((size_t)(b * 64 + oc) * 64 + (y0 + r)) * 64 + x;
            float vm = vm1[addr];
            vm = ((vm > 0.5f) ? 0.f : vm * DECAY) + acc[r][uu];
            vm1[addr] = vm;
            s1_s[r][x][ol] = (vm > 0.5f) ? (unsigned short)0x3F80 : (unsigned short)0;
        }
    }
    __syncthreads();

    // fused 2x2 maxpool -> flat[t*16+b] (spikes in {0,0x3F80} => max == bitwise OR)
    unsigned short* flat = (unsigned short*)((char*)ws + OFF_FLAT_BYTES)
                           + (size_t)(t * 16 + b) * 65536;
#pragma unroll
    for (int j = 0; j < 4; ++j) {
        int idx = tid + j * 256;                 // 0..1023 = ol*64 + y2l*32 + x2
        int ol = idx >> 6, y2l = (idx >> 5) & 1, x2 = idx & 31;
        int r0 = y2l * 2;
        unsigned short v = (unsigned short)(s1_s[r0][2 * x2][ol] | s1_s[r0][2 * x2 + 1][ol]
                                          | s1_s[r0 + 1][2 * x2][ol] | s1_s[r0 + 1][2 * x2 + 1][ol]);
        flat[(g * 16 + ol) * 1024 + (y4 * 2 + y2l) * 32 + x2] = v;
    }
}

// ---------------- dense0 via bf16 MFMA, hi/lo weight split ----------------
// v2: A fragments loaded per-lane directly from L2-resident flat (same elements, same
// MFMA order as verified version -> bit-identical); N-tile 32 -> grid (64,16) = 1024
// blocks = 4 blocks/CU (2x occupancy), LDS 9 KB. Grid (kc, nb): XCD = kc%8 -> all 16
// nb-blocks of a kc share one XCD L2 (flat chunk HBM-fetched ~once; FETCH ~= D0 134 MB).
__global__ __launch_bounds__(256) void dense0_mfma(const float* __restrict__ D0,
                                                   float* __restrict__ ws) {
    __shared__ unsigned short Bh_s[32 * 72];   // [n][k] bf16 hi
    __shared__ unsigned short Bl_s[32 * 72];   // [n][k] bf16 lo
    int tid = threadIdx.x;
    int kc = blockIdx.x, nb = blockIdx.y;      // nb 0..15 (32-wide n tile)
    int lane = tid & 63, w = tid >> 6, q = lane >> 4, r = lane & 15;
    const unsigned short* flat = (const unsigned short*)((const char*)ws + OFF_FLAT_BYTES);
    const size_t kbase = (size_t)kc * KCHUNK;

    floatx4 acc[4][2];
#pragma unroll
    for (int i = 0; i < 4; ++i)
#pragma unroll
        for (int j = 0; j < 2; ++j) acc[i][j] = (floatx4){0.f, 0.f, 0.f, 0.f};

    int bn = tid & 31, bk8 = tid >> 5;         // 8 threads/row, 8 k-floats each
    const float* bG = D0 + (size_t)(nb * 32 + bn) * 65536 + kbase + bk8 * 8;
    const unsigned short* aB = flat + kbase + q * 8;

    for (int k0 = 0; k0 < KCHUNK; k0 += 64) {
        // A fragments: direct per-lane loads (row m = w*64+mi*16+r), L2-resident
        short8 af[2][4];
#pragma unroll
        for (int ksi = 0; ksi < 2; ++ksi)
#pragma unroll
            for (int mi = 0; mi < 4; ++mi)
                af[ksi][mi] = *(const short8*)(aB + (size_t)(w * 64 + mi * 16 + r) * 65536
                                               + k0 + ksi * 32);
        float4 bv0 = *(const float4*)(bG + k0);
        float4 bv1 = *(const float4*)(bG + k0 + 4);

        __syncthreads();   // previous tile's B_s reads complete
        {
            float f[8] = {bv0.x, bv0.y, bv0.z, bv0.w, bv1.x, bv1.y, bv1.z, bv1.w};
            unsigned hw[4], lw[4];
#pragma unroll
            for (int j = 0; j < 4; ++j) {
                unsigned short h0 = f2bf_rne(f[2*j]),   h1 = f2bf_rne(f[2*j+1]);
                unsigned short l0 = f2bf_rne(f[2*j]   - bf2f(h0));
                unsigned short l1 = f2bf_rne(f[2*j+1] - bf2f(h1));
                hw[j] = (unsigned)h0 | ((unsigned)h1 << 16);
                lw[j] = (unsigned)l0 | ((unsigned)l1 << 16);
            }
            *(uint4*)&Bh_s[bn * 72 + bk8 * 8] = make_uint4(hw[0], hw[1], hw[2], hw[3]);
            *(uint4*)&Bl_s[bn * 72 + bk8 * 8] = make_uint4(lw[0], lw[1], lw[2], lw[3]);
        }
        __syncthreads();

#pragma unroll
        for (int ksi = 0; ksi < 2; ++ksi) {
#pragma unroll
            for (int ni = 0; ni < 2; ++ni) {
                short8 bh = *(const short8*)&Bh_s[(ni * 16 + r) * 72 + ksi * 32 + q * 8];
                short8 bl = *(const short8*)&Bl_s[(ni * 16 + r) * 72 + ksi * 32 + q * 8];
#pragma unroll
                for (int mi = 0; mi < 4; ++mi) {
                    acc[mi][ni] = __builtin_amdgcn_mfma_f32_16x16x32_bf16(af[ksi][mi], bh, acc[mi][ni], 0, 0, 0);
                    acc[mi][ni] = __builtin_amdgcn_mfma_f32_16x16x32_bf16(af[ksi][mi], bl, acc[mi][ni], 0, 0, 0);
                }
            }
        }
    }

    float* part = (float*)((char*)ws + OFF_PART_BYTES);
#pragma unroll
    for (int mi = 0; mi < 4; ++mi)
#pragma unroll
        for (int ni = 0; ni < 2; ++ni) {
            int m0 = w * 64 + mi * 16 + q * 4;
            int n  = nb * 32 + ni * 16 + r;
#pragma unroll
            for (int rg = 0; rg < 4; ++rg)
                part[((size_t)kc * 256 + m0 + rg) * 512 + n] = acc[mi][ni][rg];
        }
}

// ---------------- reduce split-K partials (verified) ----------------
__global__ __launch_bounds__(256) void reduce_part(float* __restrict__ ws) {
    int e = blockIdx.x * 256 + threadIdx.x;    // 0..131071
    const float* part = (const float*)((const char*)ws + OFF_PART_BYTES);
    float s = 0.f;
#pragma unroll 8
    for (int c = 0; c < KSPLIT; ++c) s += part[(size_t)c * 131072 + e];
    ((float*)((char*)ws + OFF_I_BYTES))[e] = s;
}

// ---------------- tail: LIF2 + dense1 + LIF3 + acc over all t (verified) ----------------
__global__ __launch_bounds__(512) void tail_kernel(const float* __restrict__ D1,
                                                   float* __restrict__ out,
                                                   const float* __restrict__ ws_ro) {
    __shared__ float s2l[16][512];
    __shared__ float d1l[11 * 512];
    __shared__ float pb[2][176];
    int tid = threadIdx.x;
    for (int i = tid; i < 11 * 512; i += 512) d1l[i] = D1[i];
    const float* Ibuf = (const float*)((const char*)ws_ro + OFF_I_BYTES);

    float vm2[16];
#pragma unroll
    for (int i = 0; i < 16; ++i) vm2[i] = 0.f;
    unsigned s2mask = 0;
    float vm3 = 0.f, s3 = 0.f, accv = 0.f;
    int rb = tid / 11, ro = tid % 11;
    __syncthreads();

    for (int t = 0; t < TSTEPS; ++t) {
        {
            int j = tid;
#pragma unroll
            for (int b = 0; b < 16; ++b) {
                float I = Ibuf[(size_t)(t * 16 + b) * 512 + j];
                float sp = ((s2mask >> b) & 1u) ? 1.f : 0.f;
                float vm = vm2[b] * DECAY * (1.f - sp) + I;
                vm2[b] = vm;
                unsigned sb = (vm > 0.5f) ? 1u : 0u;
                s2mask = (s2mask & ~(1u << b)) | (sb << b);
                s2l[b][j] = (float)sb;
            }
        }
        __syncthreads();
        if (tid < 352) {
            int g = tid / 176, rr = tid % 176;
            int b = rr / 11, o = rr % 11;
            float p = 0.f;
            int kbase = g * 256;
            for (int k = 0; k < 256; ++k)
                p = fmaf(s2l[b][kbase + k], d1l[o * 512 + kbase + k], p);
            pb[g][rr] = p;
        }
        __syncthreads();
        if (tid < 176) {
            float I3 = pb[0][tid] + pb[1][tid];
            float vm = vm3 * DECAY * (1.f - s3) + I3;
            vm3 = vm;
            s3 = (vm > 0.5f) ? 1.f : 0.f;
            accv += s3;
        }
        __syncthreads();
    }
    if (tid < 176) out[rb * 11 + ro] = accv * (1.f / 16.f);
}

extern "C" void kernel_launch(void* const* d_in, const int* in_sizes, int n_in,
                              void* d_out, int out_size, void* d_ws, size_t ws_size,
                              hipStream_t stream) {
    (void)in_sizes; (void)n_in; (void)out_size; (void)ws_size;
    const float* in = (const float*)d_in[0];
    const float* W0 = (const float*)d_in[1];
    const float* W1 = (const float*)d_in[2];
    const float* D0 = (const float*)d_in[3];
    const float* D1 = (const float*)d_in[4];
    float* ws = (float*)d_ws;
    float* out = (float*)d_out;

    // zero persistent LIF state (vm0, vm1) + padded s0 (guard ring) — ws is poisoned each call
    hipMemsetAsync(d_ws, 0, ZERO_BYTES, stream);
    prep_weights<<<99, 256, 0, stream>>>(W0, W1, ws);

    for (int t = 0; t < TSTEPS; ++t) {
        conv0_lif<<<dim3(64, 16), 256, 0, stream>>>(in, ws, t);
        conv1_lif<<<dim3(16, 16, 4), 256, 0, stream>>>(ws, t);
    }
    dense0_mfma<<<dim3(KSPLIT, 16), 256, 0, stream>>>(D0, ws);
    reduce_part<<<512, 256, 0, stream>>>(ws);
    tail_kernel<<<1, 512, 0, stream>>>(D1, out, ws);
}

// Round 7
// 1129.256 us; speedup vs baseline: 1.1285x; 1.1285x over previous
//
#include <hip/hip_runtime.h>
#include <hip/hip_bf16.h>
#include <stdint.h>

#define DECAY 0.951229424500714f

// problem sizes (fixed by setup_inputs)
#define BATCH 16
#define TSTEPS 16

// ---------------- ws layout (byte offsets) ----------------
// conv-phase state (dead after conv loop; overlaid by split-K partials):
#define OFF_VM0B 0u            // fp32 [16][4096][32] NHWC          8,388,608 B
#define OFF_VM1B 8388608u      // fp32 [16][64][64][64] NCHW       16,777,216 B
#define OFF_S0PB 25165824u     // bf16 [16][32][66][66] padded NCHW 4,460,544 B
#define OFF_W0TB 29626368u     // fp32 [18 (ic*9+tap)][32 oc]           2,304 B
#define OFF_W1TB 29628672u     // fp32 [2 oh][32 ic][9 k][32 oc]       73,728 B
#define ZERO_BYTES 29626368u   // vm0+vm1+s0p (guard ring must be 0)
// persistent across dense phase:
#define KSPLIT 64
#define KCHUNK (65536 / KSPLIT)        // 1024
#define OFF_PART_BYTES 0u              // fp32 [64][256][512] = 33,554,432 B (overlays dead conv state + W0t/W1t)
#define OFF_I_BYTES 33554432u          // fp32 [256][512] (m = t*16+b)
#define OFF_FLAT_BYTES 34078720u       // bf16 [256][65536]  (ends at 67,633,152 B)

typedef __attribute__((ext_vector_type(8))) short short8;
typedef __attribute__((ext_vector_type(4))) float floatx4;

__device__ inline unsigned short f2bf_rne(float f) {
    unsigned u = __float_as_uint(f);
    unsigned r = (u + 0x7FFFu + ((u >> 16) & 1u)) >> 16;
    return (unsigned short)r;
}
__device__ inline float bf2f(unsigned short h) {
    return __uint_as_float(((unsigned)h) << 16);
}

// ---------------- weight prep (once per call): exact fp32 transposes ----------------
// W1t[oh][ic][k][oc32]  (per (ic,k): 32 consecutive oc -> one float4 per 4-oc thread)
// W0t[(ic*9+tap)][oc]
__global__ __launch_bounds__(256) void prep_weights(const float* __restrict__ W0,
                                                    const float* __restrict__ W1,
                                                    float* __restrict__ ws) {
    int id = blockIdx.x * 256 + threadIdx.x;
    if (id < 18432) {
        int oh = id / 9216, rem = id % 9216;
        int ic = rem / 288, rem2 = rem % 288;
        int k = rem2 / 32, ocl = rem2 % 32;
        int oc = oh * 32 + ocl;
        float* w1t = (float*)((char*)ws + OFF_W1TB);
        w1t[id] = W1[((size_t)oc * 32 + ic) * 9 + k];
    } else if (id < 19008) {
        int e = id - 18432;
        int ict = e >> 5, oc = e & 31;      // ict = ic*9 + tap
        int ic = ict / 9, tap = ict % 9;
        float* w0t = (float*)((char*)ws + OFF_W0TB);
        w0t[ict * 32 + oc] = W0[(oc * 2 + ic) * 9 + tap];
    }
}

// ---------------- conv0 (2->32, 3x3, pad 1) + LIF0 -> s0 bf16 padded-NCHW ----------------
// Arithmetic bit-identical to the verified round-0 kernel.
__global__ __launch_bounds__(256) void conv0_lif(const float* __restrict__ in,
                                                 float* __restrict__ ws, int t) {
    int y = blockIdx.x, b = blockIdx.y;
    int tid = threadIdx.x;
    int x = tid & 63;
    int g = __builtin_amdgcn_readfirstlane(tid >> 6);   // oc group (8 oc)
    const float* xin = in + (size_t)((b * TSTEPS + t) * 2) * 4096;
    const float* w0t = (const float*)((const char*)ws + OFF_W0TB);
    float acc[8];
#pragma unroll
    for (int u = 0; u < 8; ++u) acc[u] = 0.f;
#pragma unroll
    for (int ic = 0; ic < 2; ++ic) {
#pragma unroll
        for (int dy = 0; dy < 3; ++dy) {
            int sy = y + dy - 1;
            bool vy = (unsigned)sy < 64u;
            const float* rp = xin + ic * 4096 + sy * 64;
#pragma unroll
            for (int dx = 0; dx < 3; ++dx) {
                int sx = x + dx - 1;
                float v = (vy && (unsigned)sx < 64u) ? rp[sx] : 0.f;
                v = fminf(fmaxf(v, 0.f), 1.f);          // clip(x,0,1)
                const float* wp = w0t + ((ic * 9 + dy * 3 + dx) * 32 + g * 8);
#pragma unroll
                for (int u = 0; u < 8; ++u) acc[u] = fmaf(v, wp[u], acc[u]);
            }
        }
    }
    // LIF0 on vm0 (NHWC fp32); spikes out to padded NCHW bf16 s0 (exact 0.0 / 1.0)
    float* vm0 = (float*)((char*)ws + OFF_VM0B);
    size_t pidx = ((size_t)(b * 4096 + y * 64 + x)) * 32 + g * 8;
    floatx4 v0 = *(floatx4*)(vm0 + pidx);
    floatx4 v1 = *(floatx4*)(vm0 + pidx + 4);
    unsigned short sp[8];
#pragma unroll
    for (int u = 0; u < 4; ++u) {
        float vm = ((v0[u] > 0.5f) ? 0.f : v0[u] * DECAY) + acc[u];
        v0[u] = vm;
        sp[u] = (vm > 0.5f) ? (unsigned short)0x3F80 : (unsigned short)0;
    }
#pragma unroll
    for (int u = 0; u < 4; ++u) {
        float vm = ((v1[u] > 0.5f) ? 0.f : v1[u] * DECAY) + acc[4 + u];
        v1[u] = vm;
        sp[4 + u] = (vm > 0.5f) ? (unsigned short)0x3F80 : (unsigned short)0;
    }
    *(floatx4*)(vm0 + pidx) = v0;
    *(floatx4*)(vm0 + pidx + 4) = v1;
    unsigned short* s0p = (unsigned short*)((char*)ws + OFF_S0PB);
#pragma unroll
    for (int u = 0; u < 8; ++u) {
        int c = g * 8 + u;
        s0p[((size_t)(b * 32 + c) * 66 + (y + 1)) * 66 + (x + 1)] = sp[u];
    }
}

// ---------------- conv1 (32->64, 3x3, pad 1) + LIF1 + fused 2x2 maxpool ----------------
// v5: thread = full 2x2 pool quad x 4 oc (32 accs). s0: 8 aligned dword loads/ic
// (packed bf16 pairs, in-register unpack) instead of 18 u16 loads; weights: one
// ds_read_b128 per k (LDS tile [ic][k][oc32], 36 KB) -> 9 ds/ic; pool in-register
// (no s1_s LDS, no extra barrier). 4 blocks/CU.
// BIT-EXACT: per accumulator the fma chain is sequential fp32, ic ascending (outer),
// k = 0..8 ascending (inner) — identical to the verified round-3..6 chain.
__global__ __launch_bounds__(256, 4) void conv1_lif(float* __restrict__ ws, int t) {
    __shared__ float wlds[32 * 9 * 32];          // [ic][k][oc32] = 9216 floats (36 KB)
    int tid = threadIdx.x;
    int j = tid & 31;                            // col pair: out cols 2j, 2j+1
    int o4 = tid >> 5;                           // 0..7 -> 4 oc each
    int b = blockIdx.x, y2 = blockIdx.y, oh = blockIdx.z;   // batch, pooled row, oc half
    int y0 = y2 * 2;

    // ---- stage this oc-half's weight slice (9216 floats, coalesced float4) ----
    {
        const float* wsrc = (const float*)((const char*)ws + OFF_W1TB) + (size_t)oh * 9216;
#pragma unroll
        for (int i = 0; i < 9; ++i) {
            int e = tid + i * 256;               // float4 units 0..2303
            *(float4*)&wlds[e * 4] = *(const float4*)&wsrc[e * 4];
        }
    }
    __syncthreads();

    // s0 window: padded rows y0..y0+3, packed shorts [2j..2j+3] = 2 aligned dwords/row
    const unsigned* s0u = (const unsigned*)((const char*)ws + OFF_S0PB);
    const size_t rowbase = ((size_t)b * 32) * 2178;   // uint units: 4356 shorts / 2

    float acc[8][2][2];   // [uq*? ] -> [u 0..3][r][c] ; use [4][2][2] (u indexes 4 oc)
#pragma unroll
    for (int u = 0; u < 4; ++u)
#pragma unroll
        for (int r = 0; r < 2; ++r)
#pragma unroll
            for (int c = 0; c < 2; ++c) acc[u][r][c] = 0.f;

    // uint index of (ic, padded row rr, short col 2j) = ((b*32+ic)*66 + y0+rr)*33 + j
#define LOADP(dst, icc) do {                                              \
        const unsigned* p_ = s0u + (rowbase + (size_t)(icc) * 2178        \
                                    + (size_t)y0 * 33 + j);               \
        _Pragma("unroll")                                                 \
        for (int rr_ = 0; rr_ < 4; ++rr_) {                               \
            dst[rr_][0] = p_[rr_ * 33];                                   \
            dst[rr_][1] = p_[rr_ * 33 + 1];                               \
        }                                                                 \
    } while (0)

    auto compute = [&](const unsigned (&pu)[4][2], int icc) {
        float va[4][4];
#pragma unroll
        for (int rr = 0; rr < 4; ++rr) {
            va[rr][0] = __uint_as_float(pu[rr][0] << 16);
            va[rr][1] = __uint_as_float(pu[rr][0] & 0xFFFF0000u);
            va[rr][2] = __uint_as_float(pu[rr][1] << 16);
            va[rr][3] = __uint_as_float(pu[rr][1] & 0xFFFF0000u);
        }
        const float* wic = &wlds[icc * 288 + o4 * 4];
#pragma unroll
        for (int k = 0; k < 9; ++k) {
            int kr = k / 3, kc = k - kr * 3;
            float4 wv = *(const float4*)&wic[k * 32];
            float wk[4] = {wv.x, wv.y, wv.z, wv.w};
#pragma unroll
            for (int u = 0; u < 4; ++u) {
                float w = wk[u];
#pragma unroll
                for (int r = 0; r < 2; ++r)
#pragma unroll
                    for (int c = 0; c < 2; ++c)
                        acc[u][r][c] = fmaf(va[kr + r][kc + c], w, acc[u][r][c]);
            }
        }
    };

    unsigned puA[4][2], puB[4][2];
    LOADP(puA, 0);
    for (int ic = 0; ic < 32; ic += 2) {
        LOADP(puB, ic + 1);
        compute(puA, ic);
        if (ic + 2 < 32) LOADP(puA, ic + 2);
        compute(puB, ic + 1);
    }
#undef LOADP

    // LIF1 (vm1 NCHW fp32; s_prev = vm_prev > 0.5) + in-register 2x2 pool
    float* vm1 = (float*)((char*)ws + OFF_VM1B);
    unsigned short* flat = (unsigned short*)((char*)ws + OFF_FLAT_BYTES)
                           + (size_t)(t * 16 + b) * 65536;
#pragma unroll
    for (int u = 0; u < 4; ++u) {
        int oc = oh * 32 + o4 * 4 + u;
        unsigned short por = 0;
#pragma unroll
        for (int r = 0; r < 2; ++r) {
            size_t addr = ((size_t)(b * 64 + oc) * 64 + (y0 + r)) * 64 + 2 * j;
            float2 vv = *(float2*)&vm1[addr];
            float vma = ((vv.x > 0.5f) ? 0.f : vv.x * DECAY) + acc[u][r][0];
            float vmb = ((vv.y > 0.5f) ? 0.f : vv.y * DECAY) + acc[u][r][1];
            vv.x = vma; vv.y = vmb;
            *(float2*)&vm1[addr] = vv;
            if (vma > 0.5f) por = 0x3F80;
            if (vmb > 0.5f) por = 0x3F80;
        }
        flat[oc * 1024 + y2 * 32 + j] = por;   // pool max == OR of {0,0x3F80}
    }
}

// ---------------- dense0 via bf16 MFMA, hi/lo weight split (verified round-5 code) ----------------
// Grid (kc, nb): linear block id = nb*64 + kc -> XCD = kc % 8, all 8 nb-blocks of one
// kc share an XCD L2 -> flat chunk HBM-fetched ~once (verified: FETCH 236->131 MB).
__global__ __launch_bounds__(256) void dense0_mfma(const float* __restrict__ D0,
                                                   float* __restrict__ ws) {
    __shared__ unsigned short A_s[256 * 72];   // [m][k] bf16
    __shared__ unsigned short Bh_s[64 * 72];   // [n][k] bf16 hi
    __shared__ unsigned short Bl_s[64 * 72];   // [n][k] bf16 lo
    int tid = threadIdx.x;
    int kc = blockIdx.x, nb = blockIdx.y;
    int lane = tid & 63, w = tid >> 6, q = lane >> 4, r = lane & 15;
    const unsigned short* flat = (const unsigned short*)((const char*)ws + OFF_FLAT_BYTES);
    const size_t kbase = (size_t)kc * KCHUNK;

    floatx4 acc[4][4];
#pragma unroll
    for (int i = 0; i < 4; ++i)
#pragma unroll
        for (int j = 0; j < 4; ++j) acc[i][j] = (floatx4){0.f, 0.f, 0.f, 0.f};

    const unsigned short* aG = flat + (size_t)tid * 65536 + kbase;
    int bn = tid & 63, bks = (tid >> 6) * 16;
    const float* bG = D0 + (size_t)(nb * 64 + bn) * 65536 + kbase + bks;

    for (int k0 = 0; k0 < KCHUNK; k0 += 64) {
        uint4 av[8];
#pragma unroll
        for (int i = 0; i < 8; ++i) av[i] = *(const uint4*)(aG + k0 + i * 8);
        float4 bv[4];
#pragma unroll
        for (int j = 0; j < 4; ++j) bv[j] = *(const float4*)(bG + k0 + j * 4);

        __syncthreads();
#pragma unroll
        for (int i = 0; i < 8; ++i) *(uint4*)&A_s[tid * 72 + i * 8] = av[i];

        float f[16];
#pragma unroll
        for (int j = 0; j < 4; ++j) { f[j*4+0]=bv[j].x; f[j*4+1]=bv[j].y; f[j*4+2]=bv[j].z; f[j*4+3]=bv[j].w; }
        unsigned hw[8], lw[8];
#pragma unroll
        for (int j = 0; j < 8; ++j) {
            unsigned short h0 = f2bf_rne(f[2*j]),   h1 = f2bf_rne(f[2*j+1]);
            unsigned short l0 = f2bf_rne(f[2*j]   - bf2f(h0));
            unsigned short l1 = f2bf_rne(f[2*j+1] - bf2f(h1));
            hw[j] = (unsigned)h0 | ((unsigned)h1 << 16);
            lw[j] = (unsigned)l0 | ((unsigned)l1 << 16);
        }
        *(uint4*)&Bh_s[bn * 72 + bks]     = make_uint4(hw[0], hw[1], hw[2], hw[3]);
        *(uint4*)&Bh_s[bn * 72 + bks + 8] = make_uint4(hw[4], hw[5], hw[6], hw[7]);
        *(uint4*)&Bl_s[bn * 72 + bks]     = make_uint4(lw[0], lw[1], lw[2], lw[3]);
        *(uint4*)&Bl_s[bn * 72 + bks + 8] = make_uint4(lw[4], lw[5], lw[6], lw[7]);
        __syncthreads();

#pragma unroll
        for (int ks = 0; ks < 64; ks += 32) {
            short8 af[4];
#pragma unroll
            for (int mi = 0; mi < 4; ++mi)
                af[mi] = *(const short8*)&A_s[(w * 64 + mi * 16 + r) * 72 + ks + q * 8];
#pragma unroll
            for (int ni = 0; ni < 4; ++ni) {
                short8 bh = *(const short8*)&Bh_s[(ni * 16 + r) * 72 + ks + q * 8];
                short8 bl = *(const short8*)&Bl_s[(ni * 16 + r) * 72 + ks + q * 8];
#pragma unroll
                for (int mi = 0; mi < 4; ++mi) {
                    acc[mi][ni] = __builtin_amdgcn_mfma_f32_16x16x32_bf16(af[mi], bh, acc[mi][ni], 0, 0, 0);
                    acc[mi][ni] = __builtin_amdgcn_mfma_f32_16x16x32_bf16(af[mi], bl, acc[mi][ni], 0, 0, 0);
                }
            }
        }
    }

    float* part = (float*)((char*)ws + OFF_PART_BYTES);
#pragma unroll
    for (int mi = 0; mi < 4; ++mi)
#pragma unroll
        for (int ni = 0; ni < 4; ++ni) {
            int m0 = w * 64 + mi * 16 + q * 4;
            int n  = nb * 64 + ni * 16 + r;
#pragma unroll
            for (int rg = 0; rg < 4; ++rg)
                part[((size_t)kc * 256 + m0 + rg) * 512 + n] = acc[mi][ni][rg];
        }
}

// ---------------- reduce split-K partials (verified) ----------------
__global__ __launch_bounds__(256) void reduce_part(float* __restrict__ ws) {
    int e = blockIdx.x * 256 + threadIdx.x;    // 0..131071
    const float* part = (const float*)((const char*)ws + OFF_PART_BYTES);
    float s = 0.f;
#pragma unroll 8
    for (int c = 0; c < KSPLIT; ++c) s += part[(size_t)c * 131072 + e];
    ((float*)((char*)ws + OFF_I_BYTES))[e] = s;
}

// ---------------- tail v2: one block per batch (batch-independent recurrence) ----------------
// Per-(b,j,o) arithmetic textually identical to the verified tail: same LIF2 expression,
// same two 256-long sequential fma chains per output, same pb[0]+pb[1] combine.
__global__ __launch_bounds__(512) void tail_kernel(const float* __restrict__ D1,
                                                   float* __restrict__ out,
                                                   const float* __restrict__ ws_ro) {
    __shared__ float s2l[512];
    __shared__ float d1l[11 * 512];
    __shared__ float pb[2][11];
    int b = blockIdx.x;
    int tid = threadIdx.x;
    for (int i = tid; i < 11 * 512; i += 512) d1l[i] = D1[i];
    const float* Ibuf = (const float*)((const char*)ws_ro + OFF_I_BYTES);

    float vm2 = 0.f;          // state for column j = tid of batch b
    unsigned s2 = 0u;
    float vm3 = 0.f, s3 = 0.f, accv = 0.f;   // used by tid < 11 (output o = tid)
    __syncthreads();

    for (int t = 0; t < TSTEPS; ++t) {
        // phase A: LIF2 — thread tid owns column j for this batch
        {
            float I = Ibuf[(size_t)(t * 16 + b) * 512 + tid];
            float sp = s2 ? 1.f : 0.f;
            float vm = vm2 * DECAY * (1.f - sp) + I;
            vm2 = vm;
            s2 = (vm > 0.5f) ? 1u : 0u;
            s2l[tid] = (float)s2;
        }
        __syncthreads();
        // phase B: dense1 partials (2 k-halves x 11 outputs)
        if (tid < 22) {
            int g = tid / 11, o = tid % 11;
            float p = 0.f;
            int kbase = g * 256;
            for (int k = 0; k < 256; ++k)
                p = fmaf(s2l[kbase + k], d1l[o * 512 + kbase + k], p);
            pb[g][o] = p;
        }
        __syncthreads();
        // phase C: LIF3 + acc
        if (tid < 11) {
            float I3 = pb[0][tid] + pb[1][tid];
            float vm = vm3 * DECAY * (1.f - s3) + I3;
            vm3 = vm;
            s3 = (vm > 0.5f) ? 1.f : 0.f;
            accv += s3;
        }
        __syncthreads();
    }
    if (tid < 11) out[b * 11 + tid] = accv * (1.f / 16.f);
}

extern "C" void kernel_launch(void* const* d_in, const int* in_sizes, int n_in,
                              void* d_out, int out_size, void* d_ws, size_t ws_size,
                              hipStream_t stream) {
    (void)in_sizes; (void)n_in; (void)out_size; (void)ws_size;
    const float* in = (const float*)d_in[0];
    const float* W0 = (const float*)d_in[1];
    const float* W1 = (const float*)d_in[2];
    const float* D0 = (const float*)d_in[3];
    const float* D1 = (const float*)d_in[4];
    float* ws = (float*)d_ws;
    float* out = (float*)d_out;

    // zero persistent LIF state (vm0, vm1) + padded s0 (guard ring) — ws is poisoned each call
    hipMemsetAsync(d_ws, 0, ZERO_BYTES, stream);
    prep_weights<<<75, 256, 0, stream>>>(W0, W1, ws);

    for (int t = 0; t < TSTEPS; ++t) {
        conv0_lif<<<dim3(64, 16), 256, 0, stream>>>(in, ws, t);
        conv1_lif<<<dim3(16, 32, 2), 256, 0, stream>>>(ws, t);
    }
    dense0_mfma<<<dim3(KSPLIT, 8), 256, 0, stream>>>(D0, ws);
    reduce_part<<<512, 256, 0, stream>>>(ws);
    tail_kernel<<<16, 512, 0, stream>>>(D1, out, ws);
}

// Round 8
// 696.951 us; speedup vs baseline: 1.8285x; 1.6203x over previous
//
#include <hip/hip_runtime.h>
#include <hip/hip_bf16.h>
#include <stdint.h>

#define DECAY 0.951229424500714f

// problem sizes (fixed by setup_inputs)
#define BATCH 16
#define TSTEPS 16

// ---------------- ws layout (byte offsets) ----------------
// conv phase (all dead after conv; overlaid by split-K partials):
#define OFF_S0BITS 0u          // u8 [256 tb][66][66][4 g] = dword bitmask/pixel, 4,460,544 B
#define OFF_W0TB 4460544u      // fp32 [18 (ic*9+tap)][32 oc]        2,304 B
#define OFF_W1TB 4462848u      // fp32 [2 oh][32 ic][9 k][32 oc]    73,728 B (end 4,536,576)
#define ZERO_BYTES 4460544u    // s0bits guard ring must be 0; vm0/vm1 live in REGISTERS now
// dense phase:
#define KSPLIT 64
#define KCHUNK (65536 / KSPLIT)        // 1024
#define OFF_PART_BYTES 0u              // fp32 [64][256][512] = 33,554,432 B (overlays dead conv state)
#define OFF_I_BYTES 33554432u          // fp32 [256][512] (m = t*16+b)
#define OFF_FLAT_BYTES 34078720u       // bf16 fragment-ready [8192 kgrp][256 m][8 k8] = 33,554,432 B

typedef __attribute__((ext_vector_type(8))) short short8;
typedef __attribute__((ext_vector_type(4))) float floatx4;

__device__ inline unsigned short f2bf_rne(float f) {
    unsigned u = __float_as_uint(f);
    unsigned r = (u + 0x7FFFu + ((u >> 16) & 1u)) >> 16;
    return (unsigned short)r;
}
__device__ inline float bf2f(unsigned short h) {
    return __uint_as_float(((unsigned)h) << 16);
}

// ---------------- weight prep (once per call): exact fp32 transposes ----------------
__global__ __launch_bounds__(256) void prep_weights(const float* __restrict__ W0,
                                                    const float* __restrict__ W1,
                                                    float* __restrict__ ws) {
    int id = blockIdx.x * 256 + threadIdx.x;
    if (id < 18432) {
        int oh = id / 9216, rem = id % 9216;
        int ic = rem / 288, rem2 = rem % 288;
        int k = rem2 / 32, ocl = rem2 % 32;
        int oc = oh * 32 + ocl;
        float* w1t = (float*)((char*)ws + OFF_W1TB);
        w1t[id] = W1[((size_t)oc * 32 + ic) * 9 + k];
    } else if (id < 19008) {
        int e = id - 18432;
        int ict = e >> 5, oc = e & 31;      // ict = ic*9 + tap
        int ic = ict / 9, tap = ict % 9;
        float* w0t = (float*)((char*)ws + OFF_W0TB);
        w0t[ict * 32 + oc] = W0[(oc * 2 + ic) * 9 + tap];
    }
}

// ---------------- conv0 ALL-T (2->32, 3x3, pad 1) + LIF0 -> s0 bitmask ----------------
// vm0 lives in registers across the whole t-loop (zero vm0 HBM traffic).
// Per-(t,pixel,oc) arithmetic bit-identical to the verified chain: same fma order
// (ic outer, dy, dx, u inner), same LIF algebra. Spike stored as 1 bit (byte per 8-oc
// group; 4 g-threads assemble the pixel's dword via byte-granular stores).
__global__ __launch_bounds__(256) void conv0_all(const float* __restrict__ in,
                                                 float* __restrict__ ws) {
    int b = blockIdx.x, y = blockIdx.y;       // XCD = (y*16+b)%8 = b%8
    int tid = threadIdx.x;
    int x = tid & 63;
    int g = __builtin_amdgcn_readfirstlane(tid >> 6);   // oc group (8 oc)
    const float* w0t = (const float*)((const char*)ws + OFF_W0TB);
    unsigned char* s0b = (unsigned char*)((char*)ws + OFF_S0BITS);

    float vm[8];
#pragma unroll
    for (int u = 0; u < 8; ++u) vm[u] = 0.f;

    for (int t = 0; t < TSTEPS; ++t) {
        const float* xin = in + (size_t)((b * TSTEPS + t) * 2) * 4096;
        float acc[8];
#pragma unroll
        for (int u = 0; u < 8; ++u) acc[u] = 0.f;
#pragma unroll
        for (int ic = 0; ic < 2; ++ic) {
#pragma unroll
            for (int dy = 0; dy < 3; ++dy) {
                int sy = y + dy - 1;
                bool vy = (unsigned)sy < 64u;
                const float* rp = xin + ic * 4096 + sy * 64;
#pragma unroll
                for (int dx = 0; dx < 3; ++dx) {
                    int sx = x + dx - 1;
                    float v = (vy && (unsigned)sx < 64u) ? rp[sx] : 0.f;
                    v = fminf(fmaxf(v, 0.f), 1.f);          // clip(x,0,1)
                    const float* wp = w0t + ((ic * 9 + dy * 3 + dx) * 32 + g * 8);
#pragma unroll
                    for (int u = 0; u < 8; ++u) acc[u] = fmaf(v, wp[u], acc[u]);
                }
            }
        }
        unsigned byte = 0;
#pragma unroll
        for (int u = 0; u < 8; ++u) {
            float v = ((vm[u] > 0.5f) ? 0.f : vm[u] * DECAY) + acc[u];
            vm[u] = v;
            if (v > 0.5f) byte |= (1u << u);
        }
        s0b[((size_t)(t * 16 + b) * 4356 + (size_t)(y + 1) * 66 + (x + 1)) * 4 + g] =
            (unsigned char)byte;
    }
}

// ---------------- conv1 ALL-T (32->64) + LIF1 + fused 2x2 maxpool -> frag-ready flat ----------------
// vm1 in registers across all t. s0 read as one dword bitmask per pixel (16 dwords per
// thread per t cover ALL 32 ic). va = (float)((bits>>ic)&1) gives exactly 0.0/1.0 ->
// fmaf chain is value-identical to the verified sequential fp32 chain (ic outer asc,
// k 0..8 asc). Wave-wide ballot skips ic with zero spikes in the whole window
// (skipped ic contributes exactly 0 to every acc -> value-preserving).
// Weights staged to LDS ONCE for all 16 t.
__global__ __launch_bounds__(256, 4) void conv1_all(float* __restrict__ ws) {
    __shared__ float wlds[32 * 9 * 32];          // [ic][k][oc32] for this oc-half (36 KB)
    int tid = threadIdx.x;
    int j = tid & 31;                            // out cols 2j, 2j+1
    int o4 = tid >> 5;                           // 8 quads of 4 oc
    int b = blockIdx.x, y2 = blockIdx.y, oh = blockIdx.z;   // XCD = b%8
    int y0 = y2 * 2;

    {
        const float* wsrc = (const float*)((const char*)ws + OFF_W1TB) + (size_t)oh * 9216;
#pragma unroll
        for (int i = 0; i < 9; ++i) {
            int e = tid + i * 256;
            *(float4*)&wlds[e * 4] = *(const float4*)&wsrc[e * 4];
        }
    }
    __syncthreads();

    const unsigned* s0w = (const unsigned*)((const char*)ws + OFF_S0BITS);
    unsigned short* flat2 = (unsigned short*)((char*)ws + OFF_FLAT_BYTES);

    float vm1r[4][2][2];
#pragma unroll
    for (int u = 0; u < 4; ++u)
#pragma unroll
        for (int r = 0; r < 2; ++r)
#pragma unroll
            for (int c = 0; c < 2; ++c) vm1r[u][r][c] = 0.f;

    for (int t = 0; t < TSTEPS; ++t) {
        // 16 dword bitmasks: padded rows y0..y0+3, padded cols 2j..2j+3
        unsigned bits[4][4];
        {
            const unsigned* p = s0w + (size_t)(t * 16 + b) * 4356 + (size_t)y0 * 66 + 2 * j;
#pragma unroll
            for (int rr = 0; rr < 4; ++rr)
#pragma unroll
                for (int cc = 0; cc < 4; ++cc)
                    bits[rr][cc] = p[rr * 66 + cc];
        }
        unsigned orall = 0;
#pragma unroll
        for (int rr = 0; rr < 4; ++rr)
#pragma unroll
            for (int cc = 0; cc < 4; ++cc) orall |= bits[rr][cc];

        float acc[4][2][2];
#pragma unroll
        for (int u = 0; u < 4; ++u)
#pragma unroll
            for (int r = 0; r < 2; ++r)
#pragma unroll
                for (int c = 0; c < 2; ++c) acc[u][r][c] = 0.f;

        for (int ic = 0; ic < 32; ++ic) {
            if (__ballot((orall >> ic) & 1u) == 0ull) continue;   // no spike anywhere in wave
            float va[4][4];
#pragma unroll
            for (int rr = 0; rr < 4; ++rr)
#pragma unroll
                for (int cc = 0; cc < 4; ++cc)
                    va[rr][cc] = (float)((bits[rr][cc] >> ic) & 1u);
            const float* wic = &wlds[ic * 288 + o4 * 4];
#pragma unroll
            for (int k = 0; k < 9; ++k) {
                int kr = k / 3, kc = k - kr * 3;
                float4 wv = *(const float4*)&wic[k * 32];
                float wk[4] = {wv.x, wv.y, wv.z, wv.w};
#pragma unroll
                for (int u = 0; u < 4; ++u) {
                    float w = wk[u];
#pragma unroll
                    for (int r = 0; r < 2; ++r)
#pragma unroll
                        for (int c = 0; c < 2; ++c)
                            acc[u][r][c] = fmaf(va[kr + r][kc + c], w, acc[u][r][c]);
                }
            }
        }

        // LIF1 (registers) + in-register 2x2 pool -> fragment-ready flat
        int m = t * 16 + b;
#pragma unroll
        for (int u = 0; u < 4; ++u) {
            int oc = oh * 32 + o4 * 4 + u;
            unsigned short por = 0;
#pragma unroll
            for (int r = 0; r < 2; ++r)
#pragma unroll
                for (int c = 0; c < 2; ++c) {
                    float v = vm1r[u][r][c];
                    v = ((v > 0.5f) ? 0.f : v * DECAY) + acc[u][r][c];
                    vm1r[u][r][c] = v;
                    if (v > 0.5f) por = 0x3F80;
                }
            int kg = oc * 128 + y2 * 4 + (j >> 3);       // kgrp of k = oc*1024+y2*32+j
            flat2[((size_t)kg * 256 + m) * 8 + (j & 7)] = por;
        }
    }
}

// ---------------- dense0 via bf16 MFMA, hi/lo weight split ----------------
// v3: A fragments COALESCED direct from fragment-ready flat (16 consecutive lanes read
// 256 contiguous bytes) -> A_s LDS deleted (LDS 9 KB), N-tile 32, grid (64 kc, 16 nb)
// = 1024 blocks = 4/CU. Same A/B element values, same per-acc MFMA chain order as the
// verified kernel (k0 asc, ks asc, hi then lo) -> bit-identical. XCD = kc%8: all 16
// nb-blocks of a kc share one XCD L2 (flat chunk fetched ~once).
__global__ __launch_bounds__(256) void dense0_mfma(const float* __restrict__ D0,
                                                   float* __restrict__ ws) {
    __shared__ unsigned short Bh_s[32 * 72];   // [n][k] bf16 hi
    __shared__ unsigned short Bl_s[32 * 72];   // [n][k] bf16 lo
    int tid = threadIdx.x;
    int kc = blockIdx.x, nb = blockIdx.y;
    int lane = tid & 63, w = tid >> 6, q = lane >> 4, r = lane & 15;
    const unsigned short* flat2 = (const unsigned short*)((const char*)ws + OFF_FLAT_BYTES);

    floatx4 acc[4][2];
#pragma unroll
    for (int i = 0; i < 4; ++i)
#pragma unroll
        for (int jj = 0; jj < 2; ++jj) acc[i][jj] = (floatx4){0.f, 0.f, 0.f, 0.f};

    int bn = tid & 31, bk8 = tid >> 5;         // 8 threads/row, 8 consecutive k-floats
    const float* bG = D0 + (size_t)(nb * 32 + bn) * 65536 + (size_t)kc * KCHUNK + bk8 * 8;

    for (int k0 = 0; k0 < KCHUNK; k0 += 64) {
        // A fragments: coalesced direct loads from fragment-ready flat
        short8 af[2][4];
#pragma unroll
        for (int ksi = 0; ksi < 2; ++ksi) {
            int kg = kc * 128 + (k0 >> 3) + ksi * 4 + q;
#pragma unroll
            for (int mi = 0; mi < 4; ++mi)
                af[ksi][mi] = *(const short8*)&flat2[((size_t)kg * 256
                                                     + (w * 64 + mi * 16 + r)) * 8];
        }
        float4 bv0 = *(const float4*)(bG + k0);
        float4 bv1 = *(const float4*)(bG + k0 + 4);

        __syncthreads();   // previous tile's B_s reads complete
        {
            float f[8] = {bv0.x, bv0.y, bv0.z, bv0.w, bv1.x, bv1.y, bv1.z, bv1.w};
            unsigned hw[4], lw[4];
#pragma unroll
            for (int jj = 0; jj < 4; ++jj) {
                unsigned short h0 = f2bf_rne(f[2*jj]),   h1 = f2bf_rne(f[2*jj+1]);
                unsigned short l0 = f2bf_rne(f[2*jj]   - bf2f(h0));
                unsigned short l1 = f2bf_rne(f[2*jj+1] - bf2f(h1));
                hw[jj] = (unsigned)h0 | ((unsigned)h1 << 16);
                lw[jj] = (unsigned)l0 | ((unsigned)l1 << 16);
            }
            *(uint4*)&Bh_s[bn * 72 + bk8 * 8] = make_uint4(hw[0], hw[1], hw[2], hw[3]);
            *(uint4*)&Bl_s[bn * 72 + bk8 * 8] = make_uint4(lw[0], lw[1], lw[2], lw[3]);
        }
        __syncthreads();

#pragma unroll
        for (int ksi = 0; ksi < 2; ++ksi) {
#pragma unroll
            for (int ni = 0; ni < 2; ++ni) {
                short8 bh = *(const short8*)&Bh_s[(ni * 16 + r) * 72 + ksi * 32 + q * 8];
                short8 bl = *(const short8*)&Bl_s[(ni * 16 + r) * 72 + ksi * 32 + q * 8];
#pragma unroll
                for (int mi = 0; mi < 4; ++mi) {
                    acc[mi][ni] = __builtin_amdgcn_mfma_f32_16x16x32_bf16(af[ksi][mi], bh, acc[mi][ni], 0, 0, 0);
                    acc[mi][ni] = __builtin_amdgcn_mfma_f32_16x16x32_bf16(af[ksi][mi], bl, acc[mi][ni], 0, 0, 0);
                }
            }
        }
    }

    float* part = (float*)((char*)ws + OFF_PART_BYTES);
#pragma unroll
    for (int mi = 0; mi < 4; ++mi)
#pragma unroll
        for (int ni = 0; ni < 2; ++ni) {
            int m0 = w * 64 + mi * 16 + q * 4;
            int n  = nb * 32 + ni * 16 + r;
#pragma unroll
            for (int rg = 0; rg < 4; ++rg)
                part[((size_t)kc * 256 + m0 + rg) * 512 + n] = acc[mi][ni][rg];
        }
}

// ---------------- reduce split-K partials (verified) ----------------
__global__ __launch_bounds__(256) void reduce_part(float* __restrict__ ws) {
    int e = blockIdx.x * 256 + threadIdx.x;    // 0..131071
    const float* part = (const float*)((const char*)ws + OFF_PART_BYTES);
    float s = 0.f;
#pragma unroll 8
    for (int c = 0; c < KSPLIT; ++c) s += part[(size_t)c * 131072 + e];
    ((float*)((char*)ws + OFF_I_BYTES))[e] = s;
}

// ---------------- tail v2: one block per batch (verified round-7) ----------------
__global__ __launch_bounds__(512) void tail_kernel(const float* __restrict__ D1,
                                                   float* __restrict__ out,
                                                   const float* __restrict__ ws_ro) {
    __shared__ float s2l[512];
    __shared__ float d1l[11 * 512];
    __shared__ float pb[2][11];
    int b = blockIdx.x;
    int tid = threadIdx.x;
    for (int i = tid; i < 11 * 512; i += 512) d1l[i] = D1[i];
    const float* Ibuf = (const float*)((const char*)ws_ro + OFF_I_BYTES);

    float vm2 = 0.f;
    unsigned s2 = 0u;
    float vm3 = 0.f, s3 = 0.f, accv = 0.f;
    __syncthreads();

    for (int t = 0; t < TSTEPS; ++t) {
        {
            float I = Ibuf[(size_t)(t * 16 + b) * 512 + tid];
            float sp = s2 ? 1.f : 0.f;
            float vm = vm2 * DECAY * (1.f - sp) + I;
            vm2 = vm;
            s2 = (vm > 0.5f) ? 1u : 0u;
            s2l[tid] = (float)s2;
        }
        __syncthreads();
        if (tid < 22) {
            int g = tid / 11, o = tid % 11;
            float p = 0.f;
            int kbase = g * 256;
            for (int k = 0; k < 256; ++k)
                p = fmaf(s2l[kbase + k], d1l[o * 512 + kbase + k], p);
            pb[g][o] = p;
        }
        __syncthreads();
        if (tid < 11) {
            float I3 = pb[0][tid] + pb[1][tid];
            float vm = vm3 * DECAY * (1.f - s3) + I3;
            vm3 = vm;
            s3 = (vm > 0.5f) ? 1.f : 0.f;
            accv += s3;
        }
        __syncthreads();
    }
    if (tid < 11) out[b * 11 + tid] = accv * (1.f / 16.f);
}

extern "C" void kernel_launch(void* const* d_in, const int* in_sizes, int n_in,
                              void* d_out, int out_size, void* d_ws, size_t ws_size,
                              hipStream_t stream) {
    (void)in_sizes; (void)n_in; (void)out_size; (void)ws_size;
    const float* in = (const float*)d_in[0];
    const float* W0 = (const float*)d_in[1];
    const float* W1 = (const float*)d_in[2];
    const float* D0 = (const float*)d_in[3];
    const float* D1 = (const float*)d_in[4];
    float* ws = (float*)d_ws;
    float* out = (float*)d_out;

    // zero s0 bitmask (guard ring) — vm0/vm1 now live in registers
    hipMemsetAsync(d_ws, 0, ZERO_BYTES, stream);
    prep_weights<<<75, 256, 0, stream>>>(W0, W1, ws);

    conv0_all<<<dim3(16, 64), 256, 0, stream>>>(in, ws);
    conv1_all<<<dim3(16, 32, 2), 256, 0, stream>>>(ws);

    dense0_mfma<<<dim3(KSPLIT, 16), 256, 0, stream>>>(D0, ws);
    reduce_part<<<512, 256, 0, stream>>>(ws);
    tail_kernel<<<16, 512, 0, stream>>>(D1, out, ws);
}

// Round 9
// 686.992 us; speedup vs baseline: 1.8550x; 1.0145x over previous
//
#include <hip/hip_runtime.h>
#include <hip/hip_bf16.h>
#include <stdint.h>

#define DECAY 0.951229424500714f

// problem sizes (fixed by setup_inputs)
#define BATCH 16
#define TSTEPS 16

// ---------------- ws layout (byte offsets) ----------------
// conv phase (all dead after conv; overlaid by split-K partials):
#define OFF_S0BITS 0u          // u8 [256 tb][66][66][4 g] = dword bitmask/pixel, 4,460,544 B
#define OFF_W0TB 4460544u      // fp32 [18 (ic*9+tap)][32 oc]        2,304 B
#define OFF_W1TB 4462848u      // fp32 [2 oh][32 ic][9 k][32 oc]    73,728 B (end 4,536,576)
#define ZERO_BYTES 4460544u    // s0bits guard ring must be 0; vm0/vm1 live in REGISTERS
// dense phase:
#define KSPLIT 64
#define KCHUNK (65536 / KSPLIT)        // 1024
#define OFF_PART_BYTES 0u              // fp32 [64][256][512] = 33,554,432 B (overlays dead conv state)
#define OFF_I_BYTES 33554432u          // fp32 [256][512] (m = t*16+b)
#define OFF_FLAT_BYTES 34078720u       // bf16 fragment-ready [8192 kgrp][256 m][8 k8] = 33,554,432 B

typedef __attribute__((ext_vector_type(8))) short short8;
typedef __attribute__((ext_vector_type(4))) float floatx4;

__device__ inline unsigned short f2bf_rne(float f) {
    unsigned u = __float_as_uint(f);
    unsigned r = (u + 0x7FFFu + ((u >> 16) & 1u)) >> 16;
    return (unsigned short)r;
}
__device__ inline float bf2f(unsigned short h) {
    return __uint_as_float(((unsigned)h) << 16);
}

// ---------------- weight prep (once per call): exact fp32 transposes ----------------
__global__ __launch_bounds__(256) void prep_weights(const float* __restrict__ W0,
                                                    const float* __restrict__ W1,
                                                    float* __restrict__ ws) {
    int id = blockIdx.x * 256 + threadIdx.x;
    if (id < 18432) {
        int oh = id / 9216, rem = id % 9216;
        int ic = rem / 288, rem2 = rem % 288;
        int k = rem2 / 32, ocl = rem2 % 32;
        int oc = oh * 32 + ocl;
        float* w1t = (float*)((char*)ws + OFF_W1TB);
        w1t[id] = W1[((size_t)oc * 32 + ic) * 9 + k];
    } else if (id < 19008) {
        int e = id - 18432;
        int ict = e >> 5, oc = e & 31;      // ict = ic*9 + tap
        int ic = ict / 9, tap = ict % 9;
        float* w0t = (float*)((char*)ws + OFF_W0TB);
        w0t[ict * 32 + oc] = W0[(oc * 2 + ic) * 9 + tap];
    }
}

// ---------------- conv0 ALL-T (2->32, 3x3, pad 1) + LIF0 -> s0 bitmask (verified) ----------------
__global__ __launch_bounds__(256) void conv0_all(const float* __restrict__ in,
                                                 float* __restrict__ ws) {
    int b = blockIdx.x, y = blockIdx.y;       // XCD = b%8
    int tid = threadIdx.x;
    int x = tid & 63;
    int g = __builtin_amdgcn_readfirstlane(tid >> 6);   // oc group (8 oc)
    const float* w0t = (const float*)((const char*)ws + OFF_W0TB);
    unsigned char* s0b = (unsigned char*)((char*)ws + OFF_S0BITS);

    float vm[8];
#pragma unroll
    for (int u = 0; u < 8; ++u) vm[u] = 0.f;

    for (int t = 0; t < TSTEPS; ++t) {
        const float* xin = in + (size_t)((b * TSTEPS + t) * 2) * 4096;
        float acc[8];
#pragma unroll
        for (int u = 0; u < 8; ++u) acc[u] = 0.f;
#pragma unroll
        for (int ic = 0; ic < 2; ++ic) {
#pragma unroll
            for (int dy = 0; dy < 3; ++dy) {
                int sy = y + dy - 1;
                bool vy = (unsigned)sy < 64u;
                const float* rp = xin + ic * 4096 + sy * 64;
#pragma unroll
                for (int dx = 0; dx < 3; ++dx) {
                    int sx = x + dx - 1;
                    float v = (vy && (unsigned)sx < 64u) ? rp[sx] : 0.f;
                    v = fminf(fmaxf(v, 0.f), 1.f);          // clip(x,0,1)
                    const float* wp = w0t + ((ic * 9 + dy * 3 + dx) * 32 + g * 8);
#pragma unroll
                    for (int u = 0; u < 8; ++u) acc[u] = fmaf(v, wp[u], acc[u]);
                }
            }
        }
        unsigned byte = 0;
#pragma unroll
        for (int u = 0; u < 8; ++u) {
            float v = ((vm[u] > 0.5f) ? 0.f : vm[u] * DECAY) + acc[u];
            vm[u] = v;
            if (v > 0.5f) byte |= (1u << u);
        }
        s0b[((size_t)(t * 16 + b) * 4356 + (size_t)(y + 1) * 66 + (x + 1)) * 4 + g] =
            (unsigned char)byte;
    }
}

// ---------------- conv1 ALL-T (32->64) + LIF1 + fused 2x2 maxpool (verified round-8) ----------------
__global__ __launch_bounds__(256, 4) void conv1_all(float* __restrict__ ws) {
    __shared__ float wlds[32 * 9 * 32];          // [ic][k][oc32] for this oc-half (36 KB)
    int tid = threadIdx.x;
    int j = tid & 31;                            // out cols 2j, 2j+1
    int o4 = tid >> 5;                           // 8 quads of 4 oc
    int b = blockIdx.x, y2 = blockIdx.y, oh = blockIdx.z;   // XCD = b%8
    int y0 = y2 * 2;

    {
        const float* wsrc = (const float*)((const char*)ws + OFF_W1TB) + (size_t)oh * 9216;
#pragma unroll
        for (int i = 0; i < 9; ++i) {
            int e = tid + i * 256;
            *(float4*)&wlds[e * 4] = *(const float4*)&wsrc[e * 4];
        }
    }
    __syncthreads();

    const unsigned* s0w = (const unsigned*)((const char*)ws + OFF_S0BITS);
    unsigned short* flat2 = (unsigned short*)((char*)ws + OFF_FLAT_BYTES);

    float vm1r[4][2][2];
#pragma unroll
    for (int u = 0; u < 4; ++u)
#pragma unroll
        for (int r = 0; r < 2; ++r)
#pragma unroll
            for (int c = 0; c < 2; ++c) vm1r[u][r][c] = 0.f;

    for (int t = 0; t < TSTEPS; ++t) {
        unsigned bits[4][4];
        {
            const unsigned* p = s0w + (size_t)(t * 16 + b) * 4356 + (size_t)y0 * 66 + 2 * j;
#pragma unroll
            for (int rr = 0; rr < 4; ++rr)
#pragma unroll
                for (int cc = 0; cc < 4; ++cc)
                    bits[rr][cc] = p[rr * 66 + cc];
        }
        unsigned orall = 0;
#pragma unroll
        for (int rr = 0; rr < 4; ++rr)
#pragma unroll
            for (int cc = 0; cc < 4; ++cc) orall |= bits[rr][cc];

        float acc[4][2][2];
#pragma unroll
        for (int u = 0; u < 4; ++u)
#pragma unroll
            for (int r = 0; r < 2; ++r)
#pragma unroll
                for (int c = 0; c < 2; ++c) acc[u][r][c] = 0.f;

        for (int ic = 0; ic < 32; ++ic) {
            if (__ballot((orall >> ic) & 1u) == 0ull) continue;   // exactly-zero contribution
            float va[4][4];
#pragma unroll
            for (int rr = 0; rr < 4; ++rr)
#pragma unroll
                for (int cc = 0; cc < 4; ++cc)
                    va[rr][cc] = (float)((bits[rr][cc] >> ic) & 1u);
            const float* wic = &wlds[ic * 288 + o4 * 4];
#pragma unroll
            for (int k = 0; k < 9; ++k) {
                int kr = k / 3, kc = k - kr * 3;
                float4 wv = *(const float4*)&wic[k * 32];
                float wk[4] = {wv.x, wv.y, wv.z, wv.w};
#pragma unroll
                for (int u = 0; u < 4; ++u) {
                    float w = wk[u];
#pragma unroll
                    for (int r = 0; r < 2; ++r)
#pragma unroll
                        for (int c = 0; c < 2; ++c)
                            acc[u][r][c] = fmaf(va[kr + r][kc + c], w, acc[u][r][c]);
                }
            }
        }

        int m = t * 16 + b;
#pragma unroll
        for (int u = 0; u < 4; ++u) {
            int oc = oh * 32 + o4 * 4 + u;
            unsigned short por = 0;
#pragma unroll
            for (int r = 0; r < 2; ++r)
#pragma unroll
                for (int c = 0; c < 2; ++c) {
                    float v = vm1r[u][r][c];
                    v = ((v > 0.5f) ? 0.f : v * DECAY) + acc[u][r][c];
                    vm1r[u][r][c] = v;
                    if (v > 0.5f) por = 0x3F80;
                }
            int kg = oc * 128 + y2 * 4 + (j >> 3);       // kgrp of k = oc*1024+y2*32+j
            flat2[((size_t)kg * 256 + m) * 8 + (j & 7)] = por;
        }
    }
}

// ---------------- dense0 via bf16 MFMA, hi/lo weight split ----------------
// v4 = v3 + software pipeline: double-buffered Bh/Bl, ONE barrier per k-tile, next-tile
// af/bv loads issued BEFORE the barrier (latency hides under MFMA). Element values,
// conversion math, and per-accumulator MFMA chain order (k0 asc, ksi asc, hi->lo)
// identical to the verified kernel -> bit-identical results.
// dbuf safety: iter i writes buf[(i+1)&1], whose last reads finished before barrier i.
__global__ __launch_bounds__(256) void dense0_mfma(const float* __restrict__ D0,
                                                   float* __restrict__ ws) {
    __shared__ unsigned short Bh_s[2][32 * 72];   // [buf][n][k] bf16 hi
    __shared__ unsigned short Bl_s[2][32 * 72];   // [buf][n][k] bf16 lo
    int tid = threadIdx.x;
    int kc = blockIdx.x, nb = blockIdx.y;
    int lane = tid & 63, w = tid >> 6, q = lane >> 4, r = lane & 15;
    const unsigned short* flat2 = (const unsigned short*)((const char*)ws + OFF_FLAT_BYTES);

    floatx4 acc[4][2];
#pragma unroll
    for (int i = 0; i < 4; ++i)
#pragma unroll
        for (int jj = 0; jj < 2; ++jj) acc[i][jj] = (floatx4){0.f, 0.f, 0.f, 0.f};

    int bn = tid & 31, bk8 = tid >> 5;         // 8 threads/row, 8 consecutive k-floats
    const float* bG = D0 + (size_t)(nb * 32 + bn) * 65536 + (size_t)kc * KCHUNK + bk8 * 8;

    auto convWrite = [&](int buf, float4 A, float4 B) {
        float f[8] = {A.x, A.y, A.z, A.w, B.x, B.y, B.z, B.w};
        unsigned hw[4], lw[4];
#pragma unroll
        for (int jj = 0; jj < 4; ++jj) {
            unsigned short h0 = f2bf_rne(f[2*jj]),   h1 = f2bf_rne(f[2*jj+1]);
            unsigned short l0 = f2bf_rne(f[2*jj]   - bf2f(h0));
            unsigned short l1 = f2bf_rne(f[2*jj+1] - bf2f(h1));
            hw[jj] = (unsigned)h0 | ((unsigned)h1 << 16);
            lw[jj] = (unsigned)l0 | ((unsigned)l1 << 16);
        }
        *(uint4*)&Bh_s[buf][bn * 72 + bk8 * 8] = make_uint4(hw[0], hw[1], hw[2], hw[3]);
        *(uint4*)&Bl_s[buf][bn * 72 + bk8 * 8] = make_uint4(lw[0], lw[1], lw[2], lw[3]);
    };

#define LOADA(dst, k0) do {                                                       \
        _Pragma("unroll")                                                         \
        for (int ksi_ = 0; ksi_ < 2; ++ksi_) {                                    \
            int kg_ = kc * 128 + ((k0) >> 3) + ksi_ * 4 + q;                      \
            _Pragma("unroll")                                                     \
            for (int mi_ = 0; mi_ < 4; ++mi_)                                     \
                dst[ksi_][mi_] = *(const short8*)&flat2[((size_t)kg_ * 256        \
                                              + (w * 64 + mi_ * 16 + r)) * 8];    \
        }                                                                         \
    } while (0)

    short8 afc[2][4], afn[2][4];
    float4 bv0n, bv1n;

    // prologue: tile 0
    LOADA(afc, 0);
    {
        float4 b0 = *(const float4*)(bG);
        float4 b1 = *(const float4*)(bG + 4);
        convWrite(0, b0, b1);
    }

    for (int it = 0; it < 16; ++it) {
        int cur = it & 1;
        if (it < 15) {
            int k0n = (it + 1) * 64;
            LOADA(afn, k0n);
            bv0n = *(const float4*)(bG + k0n);
            bv1n = *(const float4*)(bG + k0n + 4);
        }
        __syncthreads();   // buf[cur] ready; all reads of buf[cur^1] (iter it-1) done

        // MFMA phase (order identical to verified: ksi asc, ni asc, mi asc, hi then lo)
#pragma unroll
        for (int ksi = 0; ksi < 2; ++ksi) {
#pragma unroll
            for (int ni = 0; ni < 2; ++ni) {
                short8 bh = *(const short8*)&Bh_s[cur][(ni * 16 + r) * 72 + ksi * 32 + q * 8];
                short8 bl = *(const short8*)&Bl_s[cur][(ni * 16 + r) * 72 + ksi * 32 + q * 8];
#pragma unroll
                for (int mi = 0; mi < 4; ++mi) {
                    acc[mi][ni] = __builtin_amdgcn_mfma_f32_16x16x32_bf16(afc[ksi][mi], bh, acc[mi][ni], 0, 0, 0);
                    acc[mi][ni] = __builtin_amdgcn_mfma_f32_16x16x32_bf16(afc[ksi][mi], bl, acc[mi][ni], 0, 0, 0);
                }
            }
        }

        if (it < 15) {
            convWrite(cur ^ 1, bv0n, bv1n);
#pragma unroll
            for (int ksi = 0; ksi < 2; ++ksi)
#pragma unroll
                for (int mi = 0; mi < 4; ++mi)
                    afc[ksi][mi] = afn[ksi][mi];
        }
    }
#undef LOADA

    float* part = (float*)((char*)ws + OFF_PART_BYTES);
#pragma unroll
    for (int mi = 0; mi < 4; ++mi)
#pragma unroll
        for (int ni = 0; ni < 2; ++ni) {
            int m0 = w * 64 + mi * 16 + q * 4;
            int n  = nb * 32 + ni * 16 + r;
#pragma unroll
            for (int rg = 0; rg < 4; ++rg)
                part[((size_t)kc * 256 + m0 + rg) * 512 + n] = acc[mi][ni][rg];
        }
}

// ---------------- reduce split-K partials (verified) ----------------
__global__ __launch_bounds__(256) void reduce_part(float* __restrict__ ws) {
    int e = blockIdx.x * 256 + threadIdx.x;    // 0..131071
    const float* part = (const float*)((const char*)ws + OFF_PART_BYTES);
    float s = 0.f;
#pragma unroll 8
    for (int c = 0; c < KSPLIT; ++c) s += part[(size_t)c * 131072 + e];
    ((float*)((char*)ws + OFF_I_BYTES))[e] = s;
}

// ---------------- tail v2: one block per batch (verified) ----------------
__global__ __launch_bounds__(512) void tail_kernel(const float* __restrict__ D1,
                                                   float* __restrict__ out,
                                                   const float* __restrict__ ws_ro) {
    __shared__ float s2l[512];
    __shared__ float d1l[11 * 512];
    __shared__ float pb[2][11];
    int b = blockIdx.x;
    int tid = threadIdx.x;
    for (int i = tid; i < 11 * 512; i += 512) d1l[i] = D1[i];
    const float* Ibuf = (const float*)((const char*)ws_ro + OFF_I_BYTES);

    float vm2 = 0.f;
    unsigned s2 = 0u;
    float vm3 = 0.f, s3 = 0.f, accv = 0.f;
    __syncthreads();

    for (int t = 0; t < TSTEPS; ++t) {
        {
            float I = Ibuf[(size_t)(t * 16 + b) * 512 + tid];
            float sp = s2 ? 1.f : 0.f;
            float vm = vm2 * DECAY * (1.f - sp) + I;
            vm2 = vm;
            s2 = (vm > 0.5f) ? 1u : 0u;
            s2l[tid] = (float)s2;
        }
        __syncthreads();
        if (tid < 22) {
            int g = tid / 11, o = tid % 11;
            float p = 0.f;
            int kbase = g * 256;
            for (int k = 0; k < 256; ++k)
                p = fmaf(s2l[kbase + k], d1l[o * 512 + kbase + k], p);
            pb[g][o] = p;
        }
        __syncthreads();
        if (tid < 11) {
            float I3 = pb[0][tid] + pb[1][tid];
            float vm = vm3 * DECAY * (1.f - s3) + I3;
            vm3 = vm;
            s3 = (vm > 0.5f) ? 1.f : 0.f;
            accv += s3;
        }
        __syncthreads();
    }
    if (tid < 11) out[b * 11 + tid] = accv * (1.f / 16.f);
}

extern "C" void kernel_launch(void* const* d_in, const int* in_sizes, int n_in,
                              void* d_out, int out_size, void* d_ws, size_t ws_size,
                              hipStream_t stream) {
    (void)in_sizes; (void)n_in; (void)out_size; (void)ws_size;
    const float* in = (const float*)d_in[0];
    const float* W0 = (const float*)d_in[1];
    const float* W1 = (const float*)d_in[2];
    const float* D0 = (const float*)d_in[3];
    const float* D1 = (const float*)d_in[4];
    float* ws = (float*)d_ws;
    float* out = (float*)d_out;

    // zero s0 bitmask (guard ring) — vm0/vm1 live in registers
    hipMemsetAsync(d_ws, 0, ZERO_BYTES, stream);
    prep_weights<<<75, 256, 0, stream>>>(W0, W1, ws);

    conv0_all<<<dim3(16, 64), 256, 0, stream>>>(in, ws);
    conv1_all<<<dim3(16, 32, 2), 256, 0, stream>>>(ws);

    dense0_mfma<<<dim3(KSPLIT, 16), 256, 0, stream>>>(D0, ws);
    reduce_part<<<512, 256, 0, stream>>>(ws);
    tail_kernel<<<16, 512, 0, stream>>>(D1, out, ws);
}